// Round 2
// baseline (250.438 us; speedup 1.0000x reference)
//
#include <hip/hip_runtime.h>

// OFT rotation, bf16-MFMA version.
// out[n, r*64+c] = sum_k x[n, r*64+k] * R[r][k][c]
// R = I + 2Q + 2Q^2 + 2Q^3 + 2Q^4  =  I + 2Q + 2*Q^2*(I + Q + Q^2)   (2 matmuls)
// build_R emits R^T (layout [c][k]) in bf16 so apply's MFMA B-fragment is a
// contiguous 16B LDS read.

#define LDP 68   // fp32 LDS row stride in build_R (float4-aligned, breaks pow2)

typedef __attribute__((ext_vector_type(8))) short short8;   // 8 bf16 = 4 VGPR
typedef __attribute__((ext_vector_type(4))) float f32x4;

static __device__ __forceinline__ unsigned short f2bf(float f) {
  unsigned u = __float_as_uint(f);
  u += 0x7FFF + ((u >> 16) & 1);   // round-to-nearest-even
  return (unsigned short)(u >> 16);
}

// p += A[r0..r0+3][:] * B[:][c0..c0+3], K=64, row stride LDP
__device__ __forceinline__ void mm_tile_68(const float (*A)[LDP], const float (*Bm)[LDP],
                                           int r0, int c0, float p[4][4]) {
  for (int k = 0; k < 64; k += 4) {
    float4 bv[4], av[4];
#pragma unroll
    for (int u = 0; u < 4; ++u) bv[u] = *(const float4*)&Bm[k + u][c0];
#pragma unroll
    for (int i = 0; i < 4; ++i) av[i] = *(const float4*)&A[r0 + i][k];
#pragma unroll
    for (int u = 0; u < 4; ++u) {
      const float4 b = bv[u];
#pragma unroll
      for (int i = 0; i < 4; ++i) {
        const float a = ((const float*)&av[i])[u];
        p[i][0] += a * b.x;
        p[i][1] += a * b.y;
        p[i][2] += a * b.z;
        p[i][3] += a * b.w;
      }
    }
  }
}

// ---------------- Kernel 1: build R^T (bf16), one block per rotation block ---------

__global__ __launch_bounds__(256) void oft_build_R(const float* __restrict__ w,
                                                   unsigned* __restrict__ RT) {
  const int r = blockIdx.x;
  const int t = threadIdx.x;
  __shared__ float Q[64][LDP];
  __shared__ float P[64][LDP];
  __shared__ float T[64][LDP];

  for (int f = t; f < 64 * LDP; f += 256) (&Q[0][0])[f] = 0.f;
  __syncthreads();

  // scatter strict-upper weights (row-major triu order), skew-symmetrize
  for (int i = t; i < 2016; i += 256) {
    int row = 0, rem = i;
    while (rem >= 63 - row) { rem -= 63 - row; ++row; }
    const int col = row + 1 + rem;
    const float v = w[r * 2016 + i];
    Q[row][col] = v;
    Q[col][row] = -v;
  }
  __syncthreads();

  const int r0 = (t >> 4) * 4, c0 = (t & 15) * 4;

  // P = Q*Q ;  T = I + Q + P
  float p[4][4] = {};
  mm_tile_68(Q, Q, r0, c0, p);
#pragma unroll
  for (int i = 0; i < 4; ++i)
#pragma unroll
    for (int j = 0; j < 4; ++j) {
      P[r0 + i][c0 + j] = p[i][j];
      T[r0 + i][c0 + j] = p[i][j] + Q[r0 + i][c0 + j] + ((r0 + i) == (c0 + j) ? 1.f : 0.f);
    }
  __syncthreads();

  // R = I + 2Q + 2*(P*T)
  float p2[4][4] = {};
  mm_tile_68(P, T, r0, c0, p2);
  float acc[4][4];
#pragma unroll
  for (int i = 0; i < 4; ++i)
#pragma unroll
    for (int j = 0; j < 4; ++j)
      acc[i][j] = ((r0 + i) == (c0 + j) ? 1.f : 0.f)
                + 2.f * Q[r0 + i][c0 + j] + 2.f * p2[i][j];
  __syncthreads();          // everyone done reading T (and P/Q) in matmul 2

  // transpose into T:  T[c][k] = R[k][c]
#pragma unroll
  for (int i = 0; i < 4; ++i)
#pragma unroll
    for (int j = 0; j < 4; ++j)
      T[c0 + j][r0 + i] = acc[i][j];
  __syncthreads();

  // pack bf16 pairs, coalesced store: RT[r] is 64x64 bf16 row-major over [c][k]
#pragma unroll
  for (int i2 = 0; i2 < 8; ++i2) {
    const int f = t + 256 * i2;          // uint index, 2048 per block
    const int row = f >> 5, col = (f & 31) * 2;
    unsigned lo = f2bf(T[row][col]);
    unsigned hi = f2bf(T[row][col + 1]);
    RT[(size_t)r * 2048 + f] = lo | (hi << 16);
  }
}

// ---------------- Kernel 2: apply block-diagonal rotation with bf16 MFMA -----------

__global__ __launch_bounds__(256) void oft_apply(const float* __restrict__ x,
                                                 const unsigned* __restrict__ RT,
                                                 float* __restrict__ out) {
  const int r = blockIdx.x;          // rotation block 0..63
  const int n0 = blockIdx.y * 128;   // row tile 0..63
  const int t = threadIdx.x;

  // +8 bf16 pad -> row stride 144 B = 9*16 B: b128 frag reads conflict-free
  __shared__ __align__(16) unsigned short Xs[128][72];
  __shared__ __align__(16) unsigned short Rs[64][72];

  // stage R^T: 512 x 16B chunks, 2 per thread
  {
    const uint4* Rg = (const uint4*)(RT + (size_t)r * 2048);
    uint4 v0 = Rg[t];
    uint4 v1 = Rg[t + 256];
    *(uint4*)&Rs[t >> 3][(t & 7) * 8] = v0;
    *(uint4*)&Rs[(t + 256) >> 3][((t + 256) & 7) * 8] = v1;
  }

  // stage x tile (fp32 -> bf16): 2048 float4 chunks, 8 per thread
#pragma unroll
  for (int i = 0; i < 8; ++i) {
    const int f = t + 256 * i;
    const int row = f >> 4, c4 = (f & 15) * 4;
    float4 v = *(const float4*)&x[(size_t)(n0 + row) * 4096 + r * 64 + c4];
    ushort4 b;
    b.x = f2bf(v.x); b.y = f2bf(v.y); b.z = f2bf(v.z); b.w = f2bf(v.w);
    *(ushort4*)&Xs[row][c4] = b;
  }
  __syncthreads();

  const int lane = t & 63, w = t >> 6;
  const int lo = lane & 15, q = lane >> 4;

  // B fragments: R^T rows = output cols; B[k][n], n = lane&15, k = q*8+j (+32h)
  short8 bfr[2][4];
#pragma unroll
  for (int h = 0; h < 2; ++h)
#pragma unroll
    for (int c = 0; c < 4; ++c)
      bfr[h][c] = *(const short8*)&Rs[c * 16 + lo][h * 32 + q * 8];

  f32x4 acc[2][4];
#pragma unroll
  for (int s2 = 0; s2 < 2; ++s2)
#pragma unroll
    for (int c = 0; c < 4; ++c)
#pragma unroll
      for (int i = 0; i < 4; ++i) acc[s2][c][i] = 0.f;

#pragma unroll
  for (int s2 = 0; s2 < 2; ++s2) {
    const int s = w + 4 * s2;          // row strip 0..7
#pragma unroll
    for (int h = 0; h < 2; ++h) {
      short8 a = *(const short8*)&Xs[s * 16 + lo][h * 32 + q * 8];
#pragma unroll
      for (int c = 0; c < 4; ++c)
        acc[s2][c] = __builtin_amdgcn_mfma_f32_16x16x32_bf16(a, bfr[h][c], acc[s2][c], 0, 0, 0);
    }
  }

  // C/D layout: col = lane&15, row = (lane>>4)*4 + reg
#pragma unroll
  for (int s2 = 0; s2 < 2; ++s2) {
    const int s = w + 4 * s2;
#pragma unroll
    for (int c = 0; c < 4; ++c)
#pragma unroll
      for (int i = 0; i < 4; ++i) {
        const int row = n0 + s * 16 + q * 4 + i;
        out[(size_t)row * 4096 + r * 64 + c * 16 + lo] = acc[s2][c][i];
      }
  }
}

extern "C" void kernel_launch(void* const* d_in, const int* in_sizes, int n_in,
                              void* d_out, int out_size, void* d_ws, size_t ws_size,
                              hipStream_t stream) {
  const float* x = (const float*)d_in[0];   // (8192, 4096) fp32
  const float* w = (const float*)d_in[1];   // (64, 2016) fp32
  float* out = (float*)d_out;               // (8192, 4096) fp32
  unsigned* RTws = (unsigned*)d_ws;         // 64 * 2048 uints = 512 KB (bf16 R^T)

  oft_build_R<<<64, 256, 0, stream>>>(w, RTws);
  oft_apply<<<dim3(64, 64), 256, 0, stream>>>(x, RTws, out);
}